// Round 1
// baseline (80.322 us; speedup 1.0000x reference)
//
#include <hip/hip_runtime.h>
#include <math.h>

#define N0v 128
#define B1v 16
#define B2v 16
#define N1v 2048
#define N2v 32768
#define TOTALv 34944
#define BATCHv 1024
#define NEGV -100000000.0f

// ---- block-wide sum over 256 threads (4 waves of 64) ----
__device__ __forceinline__ float blockSum(float v, float* s_red, float* s_out) {
    __syncthreads();                     // protect s_red reuse across calls
    #pragma unroll
    for (int off = 32; off; off >>= 1) v += __shfl_down(v, off);
    const int wid = threadIdx.x >> 6, lane = threadIdx.x & 63;
    if (lane == 0) s_red[wid] = v;
    __syncthreads();
    if (threadIdx.x == 0) s_out[0] = s_red[0] + s_red[1] + s_red[2] + s_red[3];
    __syncthreads();
    return s_out[0];
}

__global__ __launch_bounds__(256) void row_kernel(
    const float* __restrict__ outs, const int* __restrict__ labels,
    float* __restrict__ out, float* __restrict__ partials)
{
    const int b   = blockIdx.x;
    const int tid = threadIdx.x;
    const float* row  = outs + (size_t)b * TOTALv;
    float*       orow = out  + (size_t)b * TOTALv;

    __shared__ float s_red[4];
    __shared__ int   s_idx[4];
    __shared__ float s_bc[8];
    __shared__ int   s_ibc[4];

    const int lab0 = labels[b * 3 + 0];
    const int lab1 = labels[b * 3 + 1];
    const int lab2 = labels[b * 3 + 2];
    const int r1   = lab1 - lab0 * B1v;

    // ---------- phase 0: out0 (128 logits): copy, argmax, CE ----------
    float v0 = -INFINITY;
    if (tid < N0v) { v0 = row[tid]; orow[tid] = v0; }
    float mv = v0; int mi = tid;
    #pragma unroll
    for (int off = 32; off; off >>= 1) {
        float ov = __shfl_down(mv, off);
        int   oi = __shfl_down(mi, off);
        if (ov > mv || (ov == mv && oi < mi)) { mv = ov; mi = oi; }
    }
    const int wid = tid >> 6, lane = tid & 63;
    if (lane == 0) { s_red[wid] = mv; s_idx[wid] = mi; }
    __syncthreads();
    if (tid == 0) {
        mv = s_red[0]; mi = s_idx[0];
        #pragma unroll
        for (int w = 1; w < 4; ++w)
            if (s_red[w] > mv || (s_red[w] == mv && s_idx[w] < mi)) { mv = s_red[w]; mi = s_idx[w]; }
        s_bc[0] = mv; s_ibc[0] = mi;
    }
    __syncthreads();
    const float max0  = s_bc[0];
    const int   pred0 = s_ibc[0];

    const float S0 = blockSum((tid < N0v) ? __expf(v0 - max0) : 0.f, s_red, &s_bc[1]);

    // ---------- phase 1: out1 (2048 logits) ----------
    const float4* rv4 = reinterpret_cast<const float4*>(row);
    float4*       ov4 = reinterpret_cast<float4*>(orow);
    const float4  neg4 = make_float4(NEGV, NEGV, NEGV, NEGV);

    // out1 occupies float4 indices [32, 32+512)
    const float4 a = rv4[32 + tid];
    const float4 c = rv4[32 + 256 + tid];
    float sl = __expf(a.x) + __expf(a.y) + __expf(a.z) + __expf(a.w)
             + __expf(c.x) + __expf(c.y) + __expf(c.z) + __expf(c.w);
    const float S1 = blockSum(sl, s_red, &s_bc[2]);

    // 16-lane group reductions: group-sumexp at lab0, group-argmax at pred0
    if (tid < 16) {
        float eg = __expf(row[N0v + lab0 * B1v + tid]);
        float gp = row[N0v + pred0 * B1v + tid];
        int   gi = tid;
        #pragma unroll
        for (int off = 8; off; off >>= 1) {
            eg += __shfl_xor(eg, off, 16);
            float ogp = __shfl_xor(gp, off, 16);
            int   ogi = __shfl_xor(gi, off, 16);
            if (ogp > gp || (ogp == gp && ogi < gi)) { gp = ogp; gi = ogi; }
        }
        if (tid == 0) { s_bc[3] = eg; s_ibc[1] = gi; }
        // group-sumexp for level-2 at lab1 done below by lanes 0..15 too
    }
    __syncthreads();
    const float Sg1      = s_bc[3];
    const int   pred1_in = s_ibc[1];
    const int   pred1    = pred0 * B1v + pred1_in;

    // masked write of out1
    ov4[32 + tid]       = ((tid >> 2) == pred0)           ? a : neg4;
    ov4[32 + 256 + tid] = ((((tid + 256)) >> 2) == pred0) ? c : neg4;

    // ---------- phase 2: out2 (32768 logits), fused sumexp + masked write ----------
    // group-sumexp for level 2 (16 values at row lab1 of out2 viewed (N1,B2))
    if (tid < 16) {
        float eg2 = __expf(row[N0v + N1v + lab1 * B2v + tid]);
        #pragma unroll
        for (int off = 8; off; off >>= 1) eg2 += __shfl_xor(eg2, off, 16);
        if (tid == 0) s_bc[4] = eg2;
    }

    const float4* base  = rv4 + 544;   // 2176/4
    float4*       obase = ov4 + 544;
    float s2 = 0.f;
    #pragma unroll 4
    for (int i = 0; i < 32; ++i) {
        const int p = i * 256 + tid;
        const float4 x = base[p];
        s2 += __expf(x.x) + __expf(x.y) + __expf(x.z) + __expf(x.w);
        obase[p] = ((p >> 2) == pred1) ? x : neg4;
    }
    const float S2 = blockSum(s2, s_red, &s_bc[5]);

    if (tid == 0) {
        const float Sg2 = s_bc[4];
        const bool found0 = (pred0 != lab0);
        const bool found1 = found0 || (pred1_in != r1);
        const float t0 = row[lab0];
        const float t1 = row[N0v + lab1];
        const float t2 = row[N0v + N1v + lab2];
        const float loss0 = __logf(S0) + max0 - t0;
        const float loss1 = (found0 ? __logf(S1) : __logf(Sg1)) - t1;
        const float loss2 = (found1 ? __logf(S2) : __logf(Sg2)) - t2;
        partials[b] = loss0 + loss1 + loss2;
    }
}

__global__ __launch_bounds__(256) void loss_reduce(
    const float* __restrict__ partials, float* __restrict__ out_loss)
{
    __shared__ float sh[4];
    const int tid = threadIdx.x;
    float s = 0.f;
    for (int i = tid; i < BATCHv; i += 256) s += partials[i];
    #pragma unroll
    for (int off = 32; off; off >>= 1) s += __shfl_down(s, off);
    if ((tid & 63) == 0) sh[tid >> 6] = s;
    __syncthreads();
    if (tid == 0) *out_loss = sh[0] + sh[1] + sh[2] + sh[3];
}

extern "C" void kernel_launch(void* const* d_in, const int* in_sizes, int n_in,
                              void* d_out, int out_size, void* d_ws, size_t ws_size,
                              hipStream_t stream) {
    const float* outs   = (const float*)d_in[0];
    const int*   labels = (const int*)d_in[1];
    float*       out    = (float*)d_out;
    float*       part   = (float*)d_ws;

    row_kernel<<<BATCHv, 256, 0, stream>>>(outs, labels, out, part);
    loss_reduce<<<1, 256, 0, stream>>>(part, out + (size_t)BATCHv * TOTALv);
}